// Round 12
// baseline (887.263 us; speedup 1.0000x reference)
//
#include <hip/hip_runtime.h>
#include <hip/hip_bf16.h>

#define N_ENT   8192
#define N_USR   16384
#define CH      64
#define N_EDGEC 1000000
#define NNZC    500000
#define TOPKC   10
#define NRELM1  8
#define KSPLIT  384   // 6 limb-blocks of 64: A=[h,h,m,l,h,m], B=[h,m,h,h,l,m]
#define BKS     96    // K-step (4 steps of 96)
#define LDSP    104   // padded LDS row stride for main tiles
#define LDSTP   133   // padded row stride (floats) for the transpose chunk buffer
#define NTILE   64    // column tiles per row (8192/128)
#define NTRI    2080  // 64*65/2 upper-triangular tiles

typedef __bf16 bf16x8 __attribute__((ext_vector_type(8)));
typedef float  f32x4  __attribute__((ext_vector_type(4)));

static __device__ __forceinline__ float waveReduceSum(float v){
#pragma unroll
  for(int o=1;o<64;o<<=1) v += __shfl_xor(v,o,64);
  return v;
}
static __device__ __forceinline__ unsigned long long u64max(unsigned long long a, unsigned long long b){
  return a>b? a: b;
}
static __device__ __forceinline__ unsigned mapf(float v){
  unsigned u = __float_as_uint(v);
  return (u & 0x80000000u) ? ~u : (u | 0x80000000u);
}
static __device__ __forceinline__ float unmapf(unsigned mk){
  unsigned uo = (mk & 0x80000000u) ? (mk ^ 0x80000000u) : ~mk;
  return __uint_as_float(uo);
}
// f32 -> bf16 RTN-even (inputs finite)
static __device__ __forceinline__ ushort f2bf(float x){
  unsigned u = __float_as_uint(x);
  return (ushort)((u + 0x7FFFu + ((u>>16)&1u)) >> 16);
}
static __device__ __forceinline__ float bf2f(ushort h){
  return __uint_as_float((unsigned)h<<16);
}

// ---------------- init: residuals + working copies in one dispatch ----------------
__global__ __launch_bounds__(256) void k_init(const float* __restrict__ ue,
                                              const float* __restrict__ ee,
                                              float* __restrict__ usr_res,
                                              float* __restrict__ cur_usr,
                                              float* __restrict__ ent_res,
                                              float* __restrict__ cur_ent){
  int i = blockIdx.x*256 + threadIdx.x;                 // float4 index
  float4 v = ((const float4*)ue)[i];
  ((float4*)usr_res)[i] = v;
  ((float4*)cur_usr)[i] = v;
  if(i < N_ENT*(CH/4)){
    float4 w = ((const float4*)ee)[i];
    ((float4*)ent_res)[i] = w;
    ((float4*)cur_ent)[i] = w;
  }
}

// ---------------- sorting (counting sort by segment key) ----------------
__global__ void k_hist(const int* __restrict__ keys, int n, int* __restrict__ hist){
  int i = blockIdx.x*blockDim.x + threadIdx.x;
  int stride = gridDim.x*blockDim.x;
  for(; i<n; i+=stride) atomicAdd(&hist[keys[i]], 1);
}

__global__ __launch_bounds__(1024) void k_scan(const int* __restrict__ hist,
                                               int* __restrict__ start,
                                               int* __restrict__ cursor, int n){
  __shared__ int part[1024];
  int t = threadIdx.x;
  int chunk = n/1024;
  int base = t*chunk;
  int s = 0;
  for(int i=0;i<chunk;i++) s += hist[base+i];
  part[t] = s; __syncthreads();
  for(int off=1; off<1024; off<<=1){
    int v = (t>=off) ? part[t-off] : 0;
    __syncthreads();
    part[t] += v;
    __syncthreads();
  }
  int run = (t==0) ? 0 : part[t-1];
  for(int i=0;i<chunk;i++){
    start[base+i] = run; cursor[base+i] = run;
    run += hist[base+i];
  }
  if(t==1023) start[n] = run;
}

__global__ void k_scatter_sortE(const int* __restrict__ head,
                                const int* __restrict__ tail,
                                const int* __restrict__ etype, int n,
                                int* __restrict__ cursor, int* __restrict__ trS){
  int i = blockIdx.x*blockDim.x + threadIdx.x;
  int stride = gridDim.x*blockDim.x;
  for(; i<n; i+=stride){
    int pos = atomicAdd(&cursor[head[i]], 1);
    trS[pos] = (tail[i] & 8191) | ((etype[i]-1)<<13);
  }
}

__global__ void k_scatter_sortU(const int* __restrict__ irows,
                                const int* __restrict__ icols,
                                const float* __restrict__ ivals, int n,
                                int* __restrict__ cursor,
                                int* __restrict__ icolsS, float* __restrict__ ivalsS){
  int i = blockIdx.x*blockDim.x + threadIdx.x;
  int stride = gridDim.x*blockDim.x;
  for(; i<n; i+=stride){
    int pos = atomicAdd(&cursor[irows[i]], 1);
    icolsS[pos] = icols[i];
    ivalsS[pos] = ivals[i];
  }
}

// ---------------- normalize + triple-bf16 split into A/B limb layouts ----------------
__global__ __launch_bounds__(256) void k_split(const float* __restrict__ in,
                                               ushort* __restrict__ outA,
                                               ushort* __restrict__ outB){
  int wave = threadIdx.x>>6, lane = threadIdx.x&63;
  int r = blockIdx.x*4 + wave;
  float v = in[(size_t)r*CH+lane];
  float ss = waveReduceSum(v*v);
  float x = v / sqrtf(ss);
  ushort h = f2bf(x);
  float r1 = x - bf2f(h);
  ushort m = f2bf(r1);
  float r2 = r1 - bf2f(m);
  ushort l = f2bf(r2);
  ushort* oA = outA + (size_t)r*KSPLIT;
  ushort* oB = outB + (size_t)r*KSPLIT;
  oA[lane]     =h; oA[64+lane] =h; oA[128+lane]=m;
  oA[192+lane] =l; oA[256+lane]=h; oA[320+lane]=m;
  oB[lane]     =h; oB[64+lane] =m; oB[128+lane]=h;
  oB[192+lane] =h; oB[256+lane]=l; oB[320+lane]=m;
}

// ---------------- symmetric sim GEMM (upper-triangular blocks) ----------------
__global__ __launch_bounds__(256) void k_gemm_bf16(const ushort* __restrict__ A,
                                                   const ushort* __restrict__ B,
                                                   float* __restrict__ C,
                                                   float* __restrict__ rowmax){
  __shared__ __align__(16) ushort As[128*LDSP];
  __shared__ __align__(16) ushort Bs[128*LDSP];
  const int tid = threadIdx.x, lane = tid&63, wid = tid>>6;

  // decode linear block id -> (by, bx), by<=bx   S(r) = r*64 - r(r-1)/2
  int bid = blockIdx.x;
  int by = (int)((129.0f - sqrtf(16641.0f - 8.0f*(float)bid)) * 0.5f);
  while(((by+1)*64 - ((by+1)*by)/2) <= bid) by++;
  while((by*64 - (by*(by-1))/2) > bid) by--;
  int bx = by + (bid - (by*64 - (by*(by-1))/2));

  const int bi = by*128, bj = bx*128;
  const int wr = (wid>>1)*64, wc = (wid&1)*64;
  const int r16 = lane&15, kg = lane>>4;

  f32x4 acc[4][4] = {};

  const uint4* gA = (const uint4*)A + (size_t)bi*(KSPLIT/8);
  const uint4* gB = (const uint4*)B + (size_t)bj*(KSPLIT/8);
  const int row2 = tid>>1, half = tid&1;

  for(int s=0; s<KSPLIT/BKS; ++s){
    __syncthreads();
#pragma unroll
    for(int jj=0;jj<6;jj++){
      *(uint4*)&As[row2*LDSP + half*48 + jj*8] = gA[row2*(KSPLIT/8) + s*12 + half*6 + jj];
      *(uint4*)&Bs[row2*LDSP + half*48 + jj*8] = gB[row2*(KSPLIT/8) + s*12 + half*6 + jj];
    }
    __syncthreads();
#pragma unroll
    for(int kk=0;kk<3;kk++){
      bf16x8 a[4], b[4];
#pragma unroll
      for(int m=0;m<4;m++)
        a[m] = *(const bf16x8*)&As[(wr+m*16+r16)*LDSP + kk*32 + kg*8];
#pragma unroll
      for(int n=0;n<4;n++)
        b[n] = *(const bf16x8*)&Bs[(wc+n*16+r16)*LDSP + kk*32 + kg*8];
#pragma unroll
      for(int m=0;m<4;m++)
#pragma unroll
        for(int n=0;n<4;n++)
          acc[m][n] = __builtin_amdgcn_mfma_f32_16x16x32_bf16(a[m], b[n], acc[m][n], 0,0,0);
    }
  }

  // ---- direct tile store. C/D layout: col = lane&15, row = (lane>>4)*4 + reg ----
#pragma unroll
  for(int m=0;m<4;m++){
#pragma unroll
    for(int n=0;n<4;n++){
      size_t base = (size_t)(bi + wr + m*16 + kg*4)*N_ENT + (bj + wc + n*16 + r16);
      C[base]          = acc[m][n][0];
      C[base+N_ENT]    = acc[m][n][1];
      C[base+2*N_ENT]  = acc[m][n][2];
      C[base+3*N_ENT]  = acc[m][n][3];
    }
  }

  // ---- tmax: per-row max of this tile (over cols) ----
  float tmax[4][4];   // [m][reg]
#pragma unroll
  for(int m=0;m<4;m++){
#pragma unroll
    for(int rg=0;rg<4;rg++){
      float v = acc[m][0][rg];
      v = fmaxf(v, acc[m][1][rg]);
      v = fmaxf(v, acc[m][2][rg]);
      v = fmaxf(v, acc[m][3][rg]);
#pragma unroll
      for(int o=1;o<16;o<<=1) v = fmaxf(v, __shfl_xor(v, o, 64));
      tmax[m][rg] = v;
    }
  }
  // ---- cm: per-column max of this tile (over rows), for the mirror tile ----
  float cm[4];        // [n]
#pragma unroll
  for(int n=0;n<4;n++){
    float v = acc[0][n][0];
#pragma unroll
    for(int m=0;m<4;m++)
#pragma unroll
      for(int rg=0;rg<4;rg++) v = fmaxf(v, acc[m][n][rg]);
    v = fmaxf(v, __shfl_xor(v, 16, 64));
    v = fmaxf(v, __shfl_xor(v, 32, 64));
    cm[n] = v;
  }

  __syncthreads();                  // main-loop LDS reads done everywhere
  float* rm  = (float*)Bs;          // 128 floats: row maxes (combine wc halves)
  float* cmb = ((float*)Bs) + 128;  // 128 floats: col maxes (combine wr halves)
  if(((wid&1)==0) && r16==0){
#pragma unroll
    for(int m=0;m<4;m++)
#pragma unroll
      for(int rg=0;rg<4;rg++)
        rm[wr + m*16 + kg*4 + rg] = tmax[m][rg];
  }
  if(wid<2 && kg==0){               // wr==0 waves hold cols wc..wc+63
#pragma unroll
    for(int n=0;n<4;n++) cmb[wc + n*16 + r16] = cm[n];
  }
  __syncthreads();
  if(((wid&1)==1) && r16==0){       // direct rowmax: rows bi.., tile bx
#pragma unroll
    for(int m=0;m<4;m++)
#pragma unroll
      for(int rg=0;rg<4;rg++){
        int rrow = wr + m*16 + kg*4 + rg;
        rowmax[(size_t)(bi+rrow)*NTILE + bx] = fmaxf(tmax[m][rg], rm[rrow]);
      }
  }
  if(by != bx && wid>=2 && kg==0){  // mirror rowmax: rows bj.., tile by
#pragma unroll
    for(int n=0;n<4;n++){
      int ccol = wc + n*16 + r16;
      rowmax[(size_t)(bj+ccol)*NTILE + by] = fmaxf(cm[n], cmb[ccol]);
    }
  }

  // ---- mirror tile store via chunked LDS transpose (coalesced 128B rows) ----
  if(by != bx){
    float* ldsT = (float*)As;       // 32 x LDSTP floats = 17 KB (fits in As)
    for(int q=0;q<4;q++){
      __syncthreads();
#pragma unroll
      for(int n=0;n<4;n++){
        if(((wc>>5) + (n>>1)) == q){
          int cl = ((n&1)*16) + r16;      // local col in chunk, 0..31
#pragma unroll
          for(int m=0;m<4;m++)
#pragma unroll
            for(int rg=0;rg<4;rg++)
              ldsT[cl*LDSTP + wr + m*16 + kg*4 + rg] = acc[m][n][rg];
        }
      }
      __syncthreads();
      int cr = tid>>3;                    // 0..31
      int g  = tid&7;                     // 0..7
      float* crow = C + (size_t)(bj + q*32 + cr)*N_ENT + bi;
#pragma unroll
      for(int f=0; f<4; ++f){
        int cidx = (g + f*8)*4;           // 0,32,..124 dwords
        float4 v = *(float4*)&ldsT[cr*LDSTP + cidx];
        *(float4*)&crow[cidx] = v;
      }
    }
  }
}

// ---------------- per-row top-k via tile-max pruning, one wave per row ----------------
#define CANDCAP 256
__global__ __launch_bounds__(64) void k_topk(const float* __restrict__ S,
                                             const float* __restrict__ rowmax,
                                             int* __restrict__ knn_idx,
                                             float* __restrict__ knn_val,
                                             float* __restrict__ rowsum){
  const int row = blockIdx.x;
  const int lane = threadIdx.x;
  const float4* s4 = (const float4*)(S + (size_t)row*N_ENT);

  __shared__ unsigned long long cand[CANDCAP];
  __shared__ int tlist[NTILE];
  __shared__ int cnt, tcnt;
  if(lane==0){ cnt=0; tcnt=0; }
  __syncthreads();

  // exact 10th-largest tile max (lane id breaks ties -> unique removal)
  float tm = rowmax[(size_t)row*NTILE + lane];
  unsigned long long work = ((unsigned long long)mapf(tm)<<32) | (unsigned)lane;
  unsigned long long w = 0;
  for(int sel=0; sel<TOPKC; ++sel){
    w = work;
#pragma unroll
    for(int o=1;o<64;o<<=1) w = u64max(w, __shfl_xor(w,o,64));
    if(work == w) work = 0ull;
  }
  float tauf = unmapf((unsigned)(w>>32));

  if(tm >= tauf){ int p = atomicAdd(&tcnt,1); tlist[p] = lane; }
  __syncthreads();
  int nt = tcnt;

  // scan qualifying tiles, 2 tiles per iteration (32 lanes each)
  for(int i = (lane>>5); i < nt; i += 2){
    int t  = tlist[i];
    int fo = lane&31;
    float4 v = s4[t*32 + fo];
    int c0 = t*128 + fo*4;
    float vv[4] = {v.x,v.y,v.z,v.w};
#pragma unroll
    for(int j=0;j<4;j++){
      if(vv[j] >= tauf){
        int pos = atomicAdd(&cnt,1);
        if(pos < CANDCAP)
          cand[pos] = ((unsigned long long)mapf(vv[j])<<32)
                    | (unsigned long long)(0xFFFFFFFFu - (unsigned)(c0+j));
      }
    }
  }
  __syncthreads();
  int n = cnt;

  if(n <= CANDCAP){
    unsigned long long c0 = (lane      < n) ? cand[lane]       : 0ull;
    unsigned long long c1 = (lane+64   < n) ? cand[lane+64]    : 0ull;
    unsigned long long c2 = (lane+128  < n) ? cand[lane+128]   : 0ull;
    unsigned long long c3 = (lane+192  < n) ? cand[lane+192]   : 0ull;
    float rs = 0.f;
    for(int sel=0; sel<TOPKC; ++sel){
      unsigned long long m = u64max(u64max(c0,c1), u64max(c2,c3));
#pragma unroll
      for(int o=1;o<64;o<<=1) m = u64max(m, __shfl_xor(m,o,64));
      if(c0==m) c0=0ull; else if(c1==m) c1=0ull;
      else if(c2==m) c2=0ull; else if(c3==m) c3=0ull;
      if(lane==0){
        float v = unmapf((unsigned)(m>>32));
        int col = (int)(0xFFFFFFFFu - (unsigned)(m & 0xFFFFFFFFu));
        knn_idx[row*TOPKC+sel] = col;
        knn_val[row*TOPKC+sel] = v;
        rs += v;
      }
    }
    if(lane==0) rowsum[row] = rs;
  } else {
    // pathological fallback: exact register insertion scan over the full row
    unsigned long long loc[TOPKC];
#pragma unroll
    for(int i=0;i<TOPKC;i++) loc[i]=0ull;
    for(int it=0; it<N_ENT/256; ++it){
      int vi = it*64+lane;
      float4 v = s4[vi];
      int c0i = vi*4;
      float vv[4] = {v.x,v.y,v.z,v.w};
#pragma unroll
      for(int j=0;j<4;j++){
        unsigned u = mapf(vv[j]);
        unsigned long long key = ((unsigned long long)u<<32)
                               | (unsigned long long)(0xFFFFFFFFu - (unsigned)(c0i+j));
        if(key > loc[TOPKC-1]){
          unsigned long long t = key;
#pragma unroll
          for(int z=0; z<TOPKC; ++z){
            if(t > loc[z]){ unsigned long long tmp=loc[z]; loc[z]=t; t=tmp; }
          }
        }
      }
    }
    float rs = 0.f;
    for(int sel=0; sel<TOPKC; ++sel){
      unsigned long long m = loc[0];
#pragma unroll
      for(int o=1;o<64;o<<=1) m = u64max(m, __shfl_xor(m,o,64));
      if(loc[0] == m){
#pragma unroll
        for(int z=0;z<TOPKC-1;++z) loc[z]=loc[z+1];
        loc[TOPKC-1]=0ull;
      }
      if(lane==0){
        float v = unmapf((unsigned)(m>>32));
        int col = (int)(0xFFFFFFFFu - (unsigned)(m & 0xFFFFFFFFu));
        knn_idx[row*TOPKC+sel] = col;
        knn_val[row*TOPKC+sel] = v;
        rs += v;
      }
    }
    if(lane==0) rowsum[row] = rs;
  }
}

// ---------------- q[i][r] = ||ent_i * W_r||^2 ----------------
__global__ __launch_bounds__(256) void k_q(const float* __restrict__ ent,
                                           const float* __restrict__ W,
                                           float* __restrict__ q){
  int wave=threadIdx.x>>6, lane=threadIdx.x&63;
  int r = blockIdx.x*4+wave;
  if(r>=N_ENT) return;
  float x = ent[(size_t)r*CH+lane];
#pragma unroll
  for(int rel=0; rel<NRELM1; rel++){
    float tt = x*W[rel*CH+lane];
    float s = waveReduceSum(tt*tt);
    if(lane==0) q[r*NRELM1+rel]=s;
  }
}

// ---------------- per-head edge aggregation: SINGLE PASS ----------------
// att = q_h[r]*q_t[r] <= 0.01 always (xavier-bounded W, l2-normed e), so the
// softmax max-shift is unnecessary: exp(att) in [1,1.01], no overflow.
// softmax is shift-invariant -> mathematically identical result.
__global__ __launch_bounds__(256) void k_edge_agg(
    const int* __restrict__ trS, const int* __restrict__ startE,
    const float* __restrict__ ent, const float* __restrict__ W,
    const float* __restrict__ q, float* __restrict__ agg){
  int wave=threadIdx.x>>6, lane=threadIdx.x&63;
  int h = blockIdx.x*4+wave;
  if(h>=N_ENT) return;
  int s = startE[h], e2 = startE[h+1];

  float qh[NRELM1];
#pragma unroll
  for(int r=0;r<NRELM1;r++) qh[r] = q[h*NRELM1+r];
  float wr[NRELM1];
#pragma unroll
  for(int r=0;r<NRELM1;r++) wr[r] = W[r*CH+lane];

  float dn = 0.f;       // lane-replicated (same on all 64 lanes)
  float acc = 0.f;
  for(int p=s; p<e2; p++){
    int tr = trS[p];                        // wave-uniform load
    int tl = tr & 8191, r = tr>>13;
    float e = expf(qh[r]*q[tl*NRELM1+r]);   // wave-uniform
    dn += e;
    acc = fmaf(e*wr[r], ent[(size_t)tl*CH+lane], acc);
  }
  float inv = (dn>0.f) ? 1.f/dn : 0.f;
  agg[(size_t)h*CH+lane] = acc*inv;
}

// ---------------- per-user: sparse agg + gated score + l2norm + residual ----------------
__global__ __launch_bounds__(256) void k_user(
    const int* __restrict__ icolsS, const float* __restrict__ ivalsS,
    const int* __restrict__ startU,
    const float* __restrict__ ent, const float* __restrict__ W,
    float* __restrict__ usr, float* __restrict__ usr_res){
  int wave=threadIdx.x>>6, lane=threadIdx.x&63;
  int u = blockIdx.x*4+wave;
  if(u>=N_USR) return;
  float ue = usr[(size_t)u*CH+lane];
  float l[NRELM1];
#pragma unroll
  for(int r=0;r<NRELM1;r++) l[r] = waveReduceSum(ue*W[r*CH+lane]);
  float lm = l[0];
#pragma unroll
  for(int r=1;r<NRELM1;r++) lm = fmaxf(lm,l[r]);
  float se=0.f;
#pragma unroll
  for(int r=0;r<NRELM1;r++){ l[r]=expf(l[r]-lm); se+=l[r]; }
  float inv = 1.f/se;
  float g = 0.f;
#pragma unroll
  for(int r=0;r<NRELM1;r++) g = fmaf(l[r]*inv, W[r*CH+lane], g);
  float acc=0.f;
  int s=startU[u], e2=startU[u+1];
  for(int p=s;p<e2;p++){
    acc = fmaf(ivalsS[p], ent[(size_t)icolsS[p]*CH+lane], acc);
  }
  float res = acc*(1.f+g);
  float nrm = sqrtf(waveReduceSum(res*res));
  float outv = res / fmaxf(nrm, 1e-12f);
  usr_res[(size_t)u*CH+lane] += outv;
  usr[(size_t)u*CH+lane] = outv;
}

// ---------------- entity finalize: l2norm + residual (+ fused next-hop q) ----------------
__global__ __launch_bounds__(256) void k_entfin(const float* __restrict__ agg,
                                                float* __restrict__ cur,
                                                float* __restrict__ res,
                                                const float* __restrict__ W,
                                                float* __restrict__ q, int makeq){
  int wave=threadIdx.x>>6, lane=threadIdx.x&63;
  int r = blockIdx.x*4+wave;
  if(r>=N_ENT) return;
  float v = agg[(size_t)r*CH+lane];
  float nrm = sqrtf(waveReduceSum(v*v));
  float outv = v / fmaxf(nrm, 1e-12f);
  cur[(size_t)r*CH+lane]=outv;
  res[(size_t)r*CH+lane]+=outv;
  if(makeq){
#pragma unroll
    for(int rel=0; rel<NRELM1; rel++){
      float tt = outv*W[rel*CH+lane];
      float s = waveReduceSum(tt*tt);
      if(lane==0) q[r*NRELM1+rel]=s;
    }
  }
}

// ---------------- fused adj writer: coalesced zeros, then direct patch ----------------
__global__ __launch_bounds__(256) void k_write_adj(
    const int* __restrict__ ki0, const float* __restrict__ kv0,
    const float* __restrict__ rs0,
    const int* __restrict__ ki1, const float* __restrict__ kv1,
    const float* __restrict__ rs1,
    float* __restrict__ adj){
  const int row = blockIdx.x;
  const int t = threadIdx.x;
  __shared__ int   cols[2*TOPKC];
  __shared__ float vals[2*TOPKC];

  if(t < TOPKC){
    int c = ki1[row*TOPKC+t];
    cols[t] = c;
    vals[t] = 0.5f * kv1[row*TOPKC+t] / (sqrtf(rs1[row]) * sqrtf(rs1[c]));
  } else if(t < 2*TOPKC){
    int i = t - TOPKC;
    int c = ki0[row*TOPKC+i];
    cols[t] = c;
    vals[t] = 0.5f * kv0[row*TOPKC+i] / (sqrtf(rs0[row]) * sqrtf(rs0[c]));
  }
  __syncthreads();
  if(t==0){
    for(int i=TOPKC;i<2*TOPKC;i++){
      int c = cols[i];
      for(int j=0;j<TOPKC;j++){
        if(cols[j]==c){ vals[j]+=vals[i]; cols[i]=-1; break; }
      }
    }
  }
  __syncthreads();

  float4* adj4 = (float4*)(adj + (size_t)row*N_ENT);
  float4 z = {0.f,0.f,0.f,0.f};
#pragma unroll
  for(int k=0;k<8;k++) adj4[k*256 + t] = z;
  __syncthreads();
  if(t < 2*TOPKC){
    int c = cols[t];
    if(c >= 0) adj[(size_t)row*N_ENT + c] = vals[t];
  }
}

extern "C" void kernel_launch(void* const* d_in, const int* in_sizes, int n_in,
                              void* d_out, int out_size, void* d_ws, size_t ws_size,
                              hipStream_t stream){
  const float* user_emb   = (const float*)d_in[0];
  const float* entity_emb = (const float*)d_in[1];
  const int*   edge_index = (const int*)d_in[2];
  const int*   edge_type  = (const int*)d_in[3];
  const int*   inter_idx  = (const int*)d_in[4];
  const float* inter_vals = (const float*)d_in[5];
  const float* W          = (const float*)d_in[6];

  const int* head  = edge_index;
  const int* tail  = edge_index + N_EDGEC;
  const int* irows = inter_idx;
  const int* icols = inter_idx + NNZC;

  float* out     = (float*)d_out;
  float* ent_res = out;
  float* usr_res = out + (size_t)N_ENT*CH;
  float* adj     = out + (size_t)N_ENT*CH + (size_t)N_USR*CH;

  char* wp = (char*)d_ws;
  auto alloc = [&](size_t bytes)->void*{
    void* p = (void*)wp; wp += (bytes+255)/256*256; return p;
  };
  ushort* abufA  = (ushort*)alloc((size_t)N_ENT*KSPLIT*2);
  ushort* abufB  = (ushort*)alloc((size_t)N_ENT*KSPLIT*2);
  float* rowmax  = (float*)alloc((size_t)N_ENT*NTILE*4);
  float* cur_ent = (float*)alloc((size_t)N_ENT*CH*4);
  float* cur_usr = (float*)alloc((size_t)N_USR*CH*4);
  float* agg     = (float*)alloc((size_t)N_ENT*CH*4);
  float* q       = (float*)alloc((size_t)N_ENT*NRELM1*4);
  int*   histE   = (int*)alloc((size_t)N_ENT*4);
  int*   startE  = (int*)alloc((size_t)(N_ENT+1)*4);
  int*   cursorE = (int*)alloc((size_t)N_ENT*4);
  int*   trS     = (int*)alloc((size_t)N_EDGEC*4);
  int*   histU   = (int*)alloc((size_t)N_USR*4);
  int*   startU  = (int*)alloc((size_t)(N_USR+1)*4);
  int*   cursorU = (int*)alloc((size_t)N_USR*4);
  int*   icolsS  = (int*)alloc((size_t)NNZC*4);
  float* ivalsS  = (float*)alloc((size_t)NNZC*4);
  int*   knn_idx0= (int*)alloc((size_t)N_ENT*TOPKC*4);
  float* knn_val0= (float*)alloc((size_t)N_ENT*TOPKC*4);
  float* rowsum0 = (float*)alloc((size_t)N_ENT*4);
  int*   knn_idx1= (int*)alloc((size_t)N_ENT*TOPKC*4);
  float* knn_val1= (float*)alloc((size_t)N_ENT*TOPKC*4);
  float* rowsum1 = (float*)alloc((size_t)N_ENT*4);

  // init (one dispatch: residuals + working copies)
  hipMemsetAsync(histE, 0, (size_t)N_ENT*4, stream);
  hipMemsetAsync(histU, 0, (size_t)N_USR*4, stream);
  k_init<<<N_USR*(CH/4)/256,256,0,stream>>>(user_emb, entity_emb,
                                            usr_res, cur_usr, ent_res, cur_ent);

  // counting sorts with fused payload gather (edges by head, inter by row)
  k_hist<<<1024,256,0,stream>>>(head, N_EDGEC, histE);
  k_hist<<<512,256,0,stream>>>(irows, NNZC, histU);
  k_scan<<<1,1024,0,stream>>>(histE, startE, cursorE, N_ENT);
  k_scan<<<1,1024,0,stream>>>(histU, startU, cursorU, N_USR);
  k_scatter_sortE<<<1024,256,0,stream>>>(head, tail, edge_type, N_EDGEC, cursorE, trS);
  k_scatter_sortU<<<512,256,0,stream>>>(irows, icols, inter_vals, NNZC, cursorU, icolsS, ivalsS);

  // build_adj #1 on original entity_emb (sim matrix staged in the adj output region)
  k_split<<<N_ENT/4,256,0,stream>>>(entity_emb, abufA, abufB);
  k_gemm_bf16<<<NTRI,256,0,stream>>>(abufA, abufB, adj, rowmax);
  k_topk<<<N_ENT,64,0,stream>>>(adj, rowmax, knn_idx0, knn_val0, rowsum0);

  // 2 hops (q for hop0 computed once; hop1's q fused into k_entfin)
  k_q<<<N_ENT/4,256,0,stream>>>(cur_ent, W, q);
  for(int hop=0; hop<2; ++hop){
    k_edge_agg<<<N_ENT/4,256,0,stream>>>(trS, startE, cur_ent, W, q, agg);
    k_user<<<N_USR/4,256,0,stream>>>(icolsS, ivalsS, startU, cur_ent, W, cur_usr, usr_res);
    k_entfin<<<N_ENT/4,256,0,stream>>>(agg, cur_ent, ent_res, W, q, hop==0);
  }

  // build_adj #2 on entity_res_emb
  k_split<<<N_ENT/4,256,0,stream>>>(ent_res, abufA, abufB);
  k_gemm_bf16<<<NTRI,256,0,stream>>>(abufA, abufB, adj, rowmax);
  k_topk<<<N_ENT,64,0,stream>>>(adj, rowmax, knn_idx1, knn_val1, rowsum1);

  // item_adj = 0.5*new + 0.5*origin, single-pass dense write (no memset, no atomics)
  k_write_adj<<<N_ENT,256,0,stream>>>(knn_idx0, knn_val0, rowsum0,
                                      knn_idx1, knn_val1, rowsum1, adj);
}

// Round 13
// 864.933 us; speedup vs baseline: 1.0258x; 1.0258x over previous
//
#include <hip/hip_runtime.h>
#include <hip/hip_bf16.h>

#define N_ENT   8192
#define N_USR   16384
#define CH      64
#define N_EDGEC 1000000
#define NNZC    500000
#define TOPKC   10
#define NRELM1  8
#define KSPLIT  384   // 6 limb-blocks of 64: A=[h,h,m,l,h,m], B=[h,m,h,h,l,m]
#define BKS     96    // K-step (4 steps of 96)
#define LDSP    104   // padded LDS row stride for main tiles
#define LDSTP   133   // padded row stride (floats) for the transpose chunk buffer
#define NTILE   64    // column tiles per row (8192/128)
#define NTRI    2080  // 64*65/2 upper-triangular tiles

typedef __bf16 bf16x8 __attribute__((ext_vector_type(8)));
typedef float  f32x4  __attribute__((ext_vector_type(4)));

static __device__ __forceinline__ float waveReduceSum(float v){
#pragma unroll
  for(int o=1;o<64;o<<=1) v += __shfl_xor(v,o,64);
  return v;
}
static __device__ __forceinline__ unsigned long long u64max(unsigned long long a, unsigned long long b){
  return a>b? a: b;
}
static __device__ __forceinline__ unsigned mapf(float v){
  unsigned u = __float_as_uint(v);
  return (u & 0x80000000u) ? ~u : (u | 0x80000000u);
}
static __device__ __forceinline__ float unmapf(unsigned mk){
  unsigned uo = (mk & 0x80000000u) ? (mk ^ 0x80000000u) : ~mk;
  return __uint_as_float(uo);
}
// f32 -> bf16 RTN-even (inputs finite)
static __device__ __forceinline__ ushort f2bf(float x){
  unsigned u = __float_as_uint(x);
  return (ushort)((u + 0x7FFFu + ((u>>16)&1u)) >> 16);
}
static __device__ __forceinline__ float bf2f(ushort h){
  return __uint_as_float((unsigned)h<<16);
}

// ---------------- init: residuals + working copies in one dispatch ----------------
__global__ __launch_bounds__(256) void k_init(const float* __restrict__ ue,
                                              const float* __restrict__ ee,
                                              float* __restrict__ usr_res,
                                              float* __restrict__ cur_usr,
                                              float* __restrict__ ent_res,
                                              float* __restrict__ cur_ent){
  int i = blockIdx.x*256 + threadIdx.x;                 // float4 index
  float4 v = ((const float4*)ue)[i];
  ((float4*)usr_res)[i] = v;
  ((float4*)cur_usr)[i] = v;
  if(i < N_ENT*(CH/4)){
    float4 w = ((const float4*)ee)[i];
    ((float4*)ent_res)[i] = w;
    ((float4*)cur_ent)[i] = w;
  }
}

// ---------------- sorting (counting sort by segment key) ----------------
__global__ void k_hist(const int* __restrict__ keys, int n, int* __restrict__ hist){
  int i = blockIdx.x*blockDim.x + threadIdx.x;
  int stride = gridDim.x*blockDim.x;
  for(; i<n; i+=stride) atomicAdd(&hist[keys[i]], 1);
}

__global__ __launch_bounds__(1024) void k_scan(const int* __restrict__ hist,
                                               int* __restrict__ start,
                                               int* __restrict__ cursor, int n){
  __shared__ int part[1024];
  int t = threadIdx.x;
  int chunk = n/1024;
  int base = t*chunk;
  int s = 0;
  for(int i=0;i<chunk;i++) s += hist[base+i];
  part[t] = s; __syncthreads();
  for(int off=1; off<1024; off<<=1){
    int v = (t>=off) ? part[t-off] : 0;
    __syncthreads();
    part[t] += v;
    __syncthreads();
  }
  int run = (t==0) ? 0 : part[t-1];
  for(int i=0;i<chunk;i++){
    start[base+i] = run; cursor[base+i] = run;
    run += hist[base+i];
  }
  if(t==1023) start[n] = run;
}

__global__ void k_scatter_sortE(const int* __restrict__ head,
                                const int* __restrict__ tail,
                                const int* __restrict__ etype, int n,
                                int* __restrict__ cursor, int* __restrict__ trS){
  int i = blockIdx.x*blockDim.x + threadIdx.x;
  int stride = gridDim.x*blockDim.x;
  for(; i<n; i+=stride){
    int pos = atomicAdd(&cursor[head[i]], 1);
    trS[pos] = (tail[i] & 8191) | ((etype[i]-1)<<13);
  }
}

__global__ void k_scatter_sortU(const int* __restrict__ irows,
                                const int* __restrict__ icols,
                                const float* __restrict__ ivals, int n,
                                int* __restrict__ cursor,
                                int* __restrict__ icolsS, float* __restrict__ ivalsS){
  int i = blockIdx.x*blockDim.x + threadIdx.x;
  int stride = gridDim.x*blockDim.x;
  for(; i<n; i+=stride){
    int pos = atomicAdd(&cursor[irows[i]], 1);
    icolsS[pos] = icols[i];
    ivalsS[pos] = ivals[i];
  }
}

// ---------------- normalize + triple-bf16 split into A/B limb layouts ----------------
__global__ __launch_bounds__(256) void k_split(const float* __restrict__ in,
                                               ushort* __restrict__ outA,
                                               ushort* __restrict__ outB){
  int wave = threadIdx.x>>6, lane = threadIdx.x&63;
  int r = blockIdx.x*4 + wave;
  float v = in[(size_t)r*CH+lane];
  float ss = waveReduceSum(v*v);
  float x = v / sqrtf(ss);
  ushort h = f2bf(x);
  float r1 = x - bf2f(h);
  ushort m = f2bf(r1);
  float r2 = r1 - bf2f(m);
  ushort l = f2bf(r2);
  ushort* oA = outA + (size_t)r*KSPLIT;
  ushort* oB = outB + (size_t)r*KSPLIT;
  oA[lane]     =h; oA[64+lane] =h; oA[128+lane]=m;
  oA[192+lane] =l; oA[256+lane]=h; oA[320+lane]=m;
  oB[lane]     =h; oB[64+lane] =m; oB[128+lane]=h;
  oB[192+lane] =h; oB[256+lane]=l; oB[320+lane]=m;
}

// ---------------- symmetric sim GEMM (upper-triangular blocks) ----------------
__global__ __launch_bounds__(256) void k_gemm_bf16(const ushort* __restrict__ A,
                                                   const ushort* __restrict__ B,
                                                   float* __restrict__ C,
                                                   float* __restrict__ rowmax){
  __shared__ __align__(16) ushort As[128*LDSP];
  __shared__ __align__(16) ushort Bs[128*LDSP];
  const int tid = threadIdx.x, lane = tid&63, wid = tid>>6;

  // decode linear block id -> (by, bx), by<=bx   S(r) = r*64 - r(r-1)/2
  int bid = blockIdx.x;
  int by = (int)((129.0f - sqrtf(16641.0f - 8.0f*(float)bid)) * 0.5f);
  while(((by+1)*64 - ((by+1)*by)/2) <= bid) by++;
  while((by*64 - (by*(by-1))/2) > bid) by--;
  int bx = by + (bid - (by*64 - (by*(by-1))/2));

  const int bi = by*128, bj = bx*128;
  const int wr = (wid>>1)*64, wc = (wid&1)*64;
  const int r16 = lane&15, kg = lane>>4;

  f32x4 acc[4][4] = {};

  const uint4* gA = (const uint4*)A + (size_t)bi*(KSPLIT/8);
  const uint4* gB = (const uint4*)B + (size_t)bj*(KSPLIT/8);
  const int row2 = tid>>1, half = tid&1;

  for(int s=0; s<KSPLIT/BKS; ++s){
    __syncthreads();
#pragma unroll
    for(int jj=0;jj<6;jj++){
      *(uint4*)&As[row2*LDSP + half*48 + jj*8] = gA[row2*(KSPLIT/8) + s*12 + half*6 + jj];
      *(uint4*)&Bs[row2*LDSP + half*48 + jj*8] = gB[row2*(KSPLIT/8) + s*12 + half*6 + jj];
    }
    __syncthreads();
#pragma unroll
    for(int kk=0;kk<3;kk++){
      bf16x8 a[4], b[4];
#pragma unroll
      for(int m=0;m<4;m++)
        a[m] = *(const bf16x8*)&As[(wr+m*16+r16)*LDSP + kk*32 + kg*8];
#pragma unroll
      for(int n=0;n<4;n++)
        b[n] = *(const bf16x8*)&Bs[(wc+n*16+r16)*LDSP + kk*32 + kg*8];
#pragma unroll
      for(int m=0;m<4;m++)
#pragma unroll
        for(int n=0;n<4;n++)
          acc[m][n] = __builtin_amdgcn_mfma_f32_16x16x32_bf16(a[m], b[n], acc[m][n], 0,0,0);
    }
  }

  // ---- direct tile store. C/D layout: col = lane&15, row = (lane>>4)*4 + reg ----
#pragma unroll
  for(int m=0;m<4;m++){
#pragma unroll
    for(int n=0;n<4;n++){
      size_t base = (size_t)(bi + wr + m*16 + kg*4)*N_ENT + (bj + wc + n*16 + r16);
      C[base]          = acc[m][n][0];
      C[base+N_ENT]    = acc[m][n][1];
      C[base+2*N_ENT]  = acc[m][n][2];
      C[base+3*N_ENT]  = acc[m][n][3];
    }
  }

  // ---- tmax: per-row max of this tile (over cols) ----
  float tmax[4][4];   // [m][reg]
#pragma unroll
  for(int m=0;m<4;m++){
#pragma unroll
    for(int rg=0;rg<4;rg++){
      float v = acc[m][0][rg];
      v = fmaxf(v, acc[m][1][rg]);
      v = fmaxf(v, acc[m][2][rg]);
      v = fmaxf(v, acc[m][3][rg]);
#pragma unroll
      for(int o=1;o<16;o<<=1) v = fmaxf(v, __shfl_xor(v, o, 64));
      tmax[m][rg] = v;
    }
  }
  // ---- cm: per-column max of this tile (over rows), for the mirror tile ----
  float cm[4];        // [n]
#pragma unroll
  for(int n=0;n<4;n++){
    float v = acc[0][n][0];
#pragma unroll
    for(int m=0;m<4;m++)
#pragma unroll
      for(int rg=0;rg<4;rg++) v = fmaxf(v, acc[m][n][rg]);
    v = fmaxf(v, __shfl_xor(v, 16, 64));
    v = fmaxf(v, __shfl_xor(v, 32, 64));
    cm[n] = v;
  }

  __syncthreads();                  // main-loop LDS reads done everywhere
  float* rm  = (float*)Bs;          // 128 floats: row maxes (combine wc halves)
  float* cmb = ((float*)Bs) + 128;  // 128 floats: col maxes (combine wr halves)
  if(((wid&1)==0) && r16==0){
#pragma unroll
    for(int m=0;m<4;m++)
#pragma unroll
      for(int rg=0;rg<4;rg++)
        rm[wr + m*16 + kg*4 + rg] = tmax[m][rg];
  }
  if(wid<2 && kg==0){               // wr==0 waves hold cols wc..wc+63
#pragma unroll
    for(int n=0;n<4;n++) cmb[wc + n*16 + r16] = cm[n];
  }
  __syncthreads();
  if(((wid&1)==1) && r16==0){       // direct rowmax: rows bi.., tile bx
#pragma unroll
    for(int m=0;m<4;m++)
#pragma unroll
      for(int rg=0;rg<4;rg++){
        int rrow = wr + m*16 + kg*4 + rg;
        rowmax[(size_t)(bi+rrow)*NTILE + bx] = fmaxf(tmax[m][rg], rm[rrow]);
      }
  }
  if(by != bx && wid>=2 && kg==0){  // mirror rowmax: rows bj.., tile by
#pragma unroll
    for(int n=0;n<4;n++){
      int ccol = wc + n*16 + r16;
      rowmax[(size_t)(bj+ccol)*NTILE + by] = fmaxf(cm[n], cmb[ccol]);
    }
  }

  // ---- mirror tile store via chunked LDS transpose (coalesced 128B rows) ----
  if(by != bx){
    float* ldsT = (float*)As;       // 32 x LDSTP floats = 17 KB (fits in As)
    for(int q=0;q<4;q++){
      __syncthreads();
#pragma unroll
      for(int n=0;n<4;n++){
        if(((wc>>5) + (n>>1)) == q){
          int cl = ((n&1)*16) + r16;      // local col in chunk, 0..31
#pragma unroll
          for(int m=0;m<4;m++)
#pragma unroll
            for(int rg=0;rg<4;rg++)
              ldsT[cl*LDSTP + wr + m*16 + kg*4 + rg] = acc[m][n][rg];
        }
      }
      __syncthreads();
      int cr = tid>>3;                    // 0..31
      int g  = tid&7;                     // 0..7
      float* crow = C + (size_t)(bj + q*32 + cr)*N_ENT + bi;
#pragma unroll
      for(int f=0; f<4; ++f){
        int cidx = (g + f*8)*4;           // 0,32,..124 dwords
        float4 v = *(float4*)&ldsT[cr*LDSTP + cidx];
        *(float4*)&crow[cidx] = v;
      }
    }
  }
}

// ---------------- per-row top-k via tile-max pruning, one wave per row ----------------
#define CANDCAP 256
__global__ __launch_bounds__(64) void k_topk(const float* __restrict__ S,
                                             const float* __restrict__ rowmax,
                                             int* __restrict__ knn_idx,
                                             float* __restrict__ knn_val,
                                             float* __restrict__ rowsum){
  const int row = blockIdx.x;
  const int lane = threadIdx.x;
  const float4* s4 = (const float4*)(S + (size_t)row*N_ENT);

  __shared__ unsigned long long cand[CANDCAP];
  __shared__ int tlist[NTILE];
  __shared__ int cnt, tcnt;
  if(lane==0){ cnt=0; tcnt=0; }
  __syncthreads();

  // exact 10th-largest tile max (lane id breaks ties -> unique removal)
  float tm = rowmax[(size_t)row*NTILE + lane];
  unsigned long long work = ((unsigned long long)mapf(tm)<<32) | (unsigned)lane;
  unsigned long long w = 0;
  for(int sel=0; sel<TOPKC; ++sel){
    w = work;
#pragma unroll
    for(int o=1;o<64;o<<=1) w = u64max(w, __shfl_xor(w,o,64));
    if(work == w) work = 0ull;
  }
  float tauf = unmapf((unsigned)(w>>32));

  if(tm >= tauf){ int p = atomicAdd(&tcnt,1); tlist[p] = lane; }
  __syncthreads();
  int nt = tcnt;

  // scan qualifying tiles, 2 tiles per iteration (32 lanes each)
  for(int i = (lane>>5); i < nt; i += 2){
    int t  = tlist[i];
    int fo = lane&31;
    float4 v = s4[t*32 + fo];
    int c0 = t*128 + fo*4;
    float vv[4] = {v.x,v.y,v.z,v.w};
#pragma unroll
    for(int j=0;j<4;j++){
      if(vv[j] >= tauf){
        int pos = atomicAdd(&cnt,1);
        if(pos < CANDCAP)
          cand[pos] = ((unsigned long long)mapf(vv[j])<<32)
                    | (unsigned long long)(0xFFFFFFFFu - (unsigned)(c0+j));
      }
    }
  }
  __syncthreads();
  int n = cnt;

  if(n <= CANDCAP){
    unsigned long long c0 = (lane      < n) ? cand[lane]       : 0ull;
    unsigned long long c1 = (lane+64   < n) ? cand[lane+64]    : 0ull;
    unsigned long long c2 = (lane+128  < n) ? cand[lane+128]   : 0ull;
    unsigned long long c3 = (lane+192  < n) ? cand[lane+192]   : 0ull;
    float rs = 0.f;
    for(int sel=0; sel<TOPKC; ++sel){
      unsigned long long m = u64max(u64max(c0,c1), u64max(c2,c3));
#pragma unroll
      for(int o=1;o<64;o<<=1) m = u64max(m, __shfl_xor(m,o,64));
      if(c0==m) c0=0ull; else if(c1==m) c1=0ull;
      else if(c2==m) c2=0ull; else if(c3==m) c3=0ull;
      if(lane==0){
        float v = unmapf((unsigned)(m>>32));
        int col = (int)(0xFFFFFFFFu - (unsigned)(m & 0xFFFFFFFFu));
        knn_idx[row*TOPKC+sel] = col;
        knn_val[row*TOPKC+sel] = v;
        rs += v;
      }
    }
    if(lane==0) rowsum[row] = rs;
  } else {
    // pathological fallback: exact register insertion scan over the full row
    unsigned long long loc[TOPKC];
#pragma unroll
    for(int i=0;i<TOPKC;i++) loc[i]=0ull;
    for(int it=0; it<N_ENT/256; ++it){
      int vi = it*64+lane;
      float4 v = s4[vi];
      int c0i = vi*4;
      float vv[4] = {v.x,v.y,v.z,v.w};
#pragma unroll
      for(int j=0;j<4;j++){
        unsigned u = mapf(vv[j]);
        unsigned long long key = ((unsigned long long)u<<32)
                               | (unsigned long long)(0xFFFFFFFFu - (unsigned)(c0i+j));
        if(key > loc[TOPKC-1]){
          unsigned long long t = key;
#pragma unroll
          for(int z=0; z<TOPKC; ++z){
            if(t > loc[z]){ unsigned long long tmp=loc[z]; loc[z]=t; t=tmp; }
          }
        }
      }
    }
    float rs = 0.f;
    for(int sel=0; sel<TOPKC; ++sel){
      unsigned long long m = loc[0];
#pragma unroll
      for(int o=1;o<64;o<<=1) m = u64max(m, __shfl_xor(m,o,64));
      if(loc[0] == m){
#pragma unroll
        for(int z=0;z<TOPKC-1;++z) loc[z]=loc[z+1];
        loc[TOPKC-1]=0ull;
      }
      if(lane==0){
        float v = unmapf((unsigned)(m>>32));
        int col = (int)(0xFFFFFFFFu - (unsigned)(m & 0xFFFFFFFFu));
        knn_idx[row*TOPKC+sel] = col;
        knn_val[row*TOPKC+sel] = v;
        rs += v;
      }
    }
    if(lane==0) rowsum[row] = rs;
  }
}

// ---------------- q[i][r] = ||ent_i * W_r||^2 ----------------
__global__ __launch_bounds__(256) void k_q(const float* __restrict__ ent,
                                           const float* __restrict__ W,
                                           float* __restrict__ q){
  int wave=threadIdx.x>>6, lane=threadIdx.x&63;
  int r = blockIdx.x*4+wave;
  if(r>=N_ENT) return;
  float x = ent[(size_t)r*CH+lane];
#pragma unroll
  for(int rel=0; rel<NRELM1; rel++){
    float tt = x*W[rel*CH+lane];
    float s = waveReduceSum(tt*tt);
    if(lane==0) q[r*NRELM1+rel]=s;
  }
}

// ---------------- per-head edge aggregation: single pass, 4 waves per head ----------------
// att <= 0.01 always (xavier W, l2-normed e) -> shift-free softmax is exact.
// Wave w handles edges p = s+w, s+w+4,... (serial length ~len/4); LDS combine.
__global__ __launch_bounds__(256) void k_edge_agg(
    const int* __restrict__ trS, const int* __restrict__ startE,
    const float* __restrict__ ent, const float* __restrict__ W,
    const float* __restrict__ q, float* __restrict__ agg){
  const int h = blockIdx.x;
  const int wid = threadIdx.x>>6, lane = threadIdx.x&63;
  const int s = startE[h], e2 = startE[h+1];

  float qh[NRELM1];
#pragma unroll
  for(int r=0;r<NRELM1;r++) qh[r] = q[h*NRELM1+r];
  float wr[NRELM1];
#pragma unroll
  for(int r=0;r<NRELM1;r++) wr[r] = W[r*CH+lane];

  float dn = 0.f;
  float acc = 0.f;
  for(int p = s+wid; p < e2; p += 4){
    int tr = trS[p];                        // wave-uniform load
    int tl = tr & 8191, r = tr>>13;
    float e = expf(qh[r]*q[tl*NRELM1+r]);   // wave-uniform
    dn += e;
    acc = fmaf(e*wr[r], ent[(size_t)tl*CH+lane], acc);
  }

  __shared__ float accs[4][CH];
  __shared__ float dns[4];
  accs[wid][lane] = acc;
  if(lane==0) dns[wid] = dn;
  __syncthreads();
  if(wid==0){
    float a = accs[0][lane]+accs[1][lane]+accs[2][lane]+accs[3][lane];
    float d = dns[0]+dns[1]+dns[2]+dns[3];
    float inv = (d>0.f) ? 1.f/d : 0.f;
    agg[(size_t)h*CH+lane] = a*inv;
  }
}

// ---------------- per-user: sparse agg + gated score + l2norm + residual ----------------
__global__ __launch_bounds__(256) void k_user(
    const int* __restrict__ icolsS, const float* __restrict__ ivalsS,
    const int* __restrict__ startU,
    const float* __restrict__ ent, const float* __restrict__ W,
    float* __restrict__ usr, float* __restrict__ usr_res){
  int wave=threadIdx.x>>6, lane=threadIdx.x&63;
  int u = blockIdx.x*4+wave;
  if(u>=N_USR) return;
  float ue = usr[(size_t)u*CH+lane];
  float l[NRELM1];
#pragma unroll
  for(int r=0;r<NRELM1;r++) l[r] = waveReduceSum(ue*W[r*CH+lane]);
  float lm = l[0];
#pragma unroll
  for(int r=1;r<NRELM1;r++) lm = fmaxf(lm,l[r]);
  float se=0.f;
#pragma unroll
  for(int r=0;r<NRELM1;r++){ l[r]=expf(l[r]-lm); se+=l[r]; }
  float inv = 1.f/se;
  float g = 0.f;
#pragma unroll
  for(int r=0;r<NRELM1;r++) g = fmaf(l[r]*inv, W[r*CH+lane], g);
  float acc=0.f;
  int s=startU[u], e2=startU[u+1];
  for(int p=s;p<e2;p++){
    acc = fmaf(ivalsS[p], ent[(size_t)icolsS[p]*CH+lane], acc);
  }
  float res = acc*(1.f+g);
  float nrm = sqrtf(waveReduceSum(res*res));
  float outv = res / fmaxf(nrm, 1e-12f);
  usr_res[(size_t)u*CH+lane] += outv;
  usr[(size_t)u*CH+lane] = outv;
}

// ---------------- entity finalize: l2norm + residual (+ fused next-hop q) ----------------
__global__ __launch_bounds__(256) void k_entfin(const float* __restrict__ agg,
                                                float* __restrict__ cur,
                                                float* __restrict__ res,
                                                const float* __restrict__ W,
                                                float* __restrict__ q, int makeq){
  int wave=threadIdx.x>>6, lane=threadIdx.x&63;
  int r = blockIdx.x*4+wave;
  if(r>=N_ENT) return;
  float v = agg[(size_t)r*CH+lane];
  float nrm = sqrtf(waveReduceSum(v*v));
  float outv = v / fmaxf(nrm, 1e-12f);
  cur[(size_t)r*CH+lane]=outv;
  res[(size_t)r*CH+lane]+=outv;
  if(makeq){
#pragma unroll
    for(int rel=0; rel<NRELM1; rel++){
      float tt = outv*W[rel*CH+lane];
      float s = waveReduceSum(tt*tt);
      if(lane==0) q[r*NRELM1+rel]=s;
    }
  }
}

// ---------------- fused adj writer: coalesced zeros, then direct patch ----------------
__global__ __launch_bounds__(256) void k_write_adj(
    const int* __restrict__ ki0, const float* __restrict__ kv0,
    const float* __restrict__ rs0,
    const int* __restrict__ ki1, const float* __restrict__ kv1,
    const float* __restrict__ rs1,
    float* __restrict__ adj){
  const int row = blockIdx.x;
  const int t = threadIdx.x;
  __shared__ int   cols[2*TOPKC];
  __shared__ float vals[2*TOPKC];

  if(t < TOPKC){
    int c = ki1[row*TOPKC+t];
    cols[t] = c;
    vals[t] = 0.5f * kv1[row*TOPKC+t] / (sqrtf(rs1[row]) * sqrtf(rs1[c]));
  } else if(t < 2*TOPKC){
    int i = t - TOPKC;
    int c = ki0[row*TOPKC+i];
    cols[t] = c;
    vals[t] = 0.5f * kv0[row*TOPKC+i] / (sqrtf(rs0[row]) * sqrtf(rs0[c]));
  }
  __syncthreads();
  if(t==0){
    for(int i=TOPKC;i<2*TOPKC;i++){
      int c = cols[i];
      for(int j=0;j<TOPKC;j++){
        if(cols[j]==c){ vals[j]+=vals[i]; cols[i]=-1; break; }
      }
    }
  }
  __syncthreads();

  float4* adj4 = (float4*)(adj + (size_t)row*N_ENT);
  float4 z = {0.f,0.f,0.f,0.f};
#pragma unroll
  for(int k=0;k<8;k++) adj4[k*256 + t] = z;
  __syncthreads();
  if(t < 2*TOPKC){
    int c = cols[t];
    if(c >= 0) adj[(size_t)row*N_ENT + c] = vals[t];
  }
}

extern "C" void kernel_launch(void* const* d_in, const int* in_sizes, int n_in,
                              void* d_out, int out_size, void* d_ws, size_t ws_size,
                              hipStream_t stream){
  const float* user_emb   = (const float*)d_in[0];
  const float* entity_emb = (const float*)d_in[1];
  const int*   edge_index = (const int*)d_in[2];
  const int*   edge_type  = (const int*)d_in[3];
  const int*   inter_idx  = (const int*)d_in[4];
  const float* inter_vals = (const float*)d_in[5];
  const float* W          = (const float*)d_in[6];

  const int* head  = edge_index;
  const int* tail  = edge_index + N_EDGEC;
  const int* irows = inter_idx;
  const int* icols = inter_idx + NNZC;

  float* out     = (float*)d_out;
  float* ent_res = out;
  float* usr_res = out + (size_t)N_ENT*CH;
  float* adj     = out + (size_t)N_ENT*CH + (size_t)N_USR*CH;

  char* wp = (char*)d_ws;
  auto alloc = [&](size_t bytes)->void*{
    void* p = (void*)wp; wp += (bytes+255)/256*256; return p;
  };
  ushort* abufA  = (ushort*)alloc((size_t)N_ENT*KSPLIT*2);
  ushort* abufB  = (ushort*)alloc((size_t)N_ENT*KSPLIT*2);
  float* rowmax  = (float*)alloc((size_t)N_ENT*NTILE*4);
  float* cur_ent = (float*)alloc((size_t)N_ENT*CH*4);
  float* cur_usr = (float*)alloc((size_t)N_USR*CH*4);
  float* agg     = (float*)alloc((size_t)N_ENT*CH*4);
  float* q       = (float*)alloc((size_t)N_ENT*NRELM1*4);
  int*   histE   = (int*)alloc((size_t)N_ENT*4);
  int*   startE  = (int*)alloc((size_t)(N_ENT+1)*4);
  int*   cursorE = (int*)alloc((size_t)N_ENT*4);
  int*   trS     = (int*)alloc((size_t)N_EDGEC*4);
  int*   histU   = (int*)alloc((size_t)N_USR*4);
  int*   startU  = (int*)alloc((size_t)(N_USR+1)*4);
  int*   cursorU = (int*)alloc((size_t)N_USR*4);
  int*   icolsS  = (int*)alloc((size_t)NNZC*4);
  float* ivalsS  = (float*)alloc((size_t)NNZC*4);
  int*   knn_idx0= (int*)alloc((size_t)N_ENT*TOPKC*4);
  float* knn_val0= (float*)alloc((size_t)N_ENT*TOPKC*4);
  float* rowsum0 = (float*)alloc((size_t)N_ENT*4);
  int*   knn_idx1= (int*)alloc((size_t)N_ENT*TOPKC*4);
  float* knn_val1= (float*)alloc((size_t)N_ENT*TOPKC*4);
  float* rowsum1 = (float*)alloc((size_t)N_ENT*4);

  // init (one dispatch: residuals + working copies)
  hipMemsetAsync(histE, 0, (size_t)N_ENT*4, stream);
  hipMemsetAsync(histU, 0, (size_t)N_USR*4, stream);
  k_init<<<N_USR*(CH/4)/256,256,0,stream>>>(user_emb, entity_emb,
                                            usr_res, cur_usr, ent_res, cur_ent);

  // counting sorts with fused payload gather (edges by head, inter by row)
  k_hist<<<1024,256,0,stream>>>(head, N_EDGEC, histE);
  k_hist<<<512,256,0,stream>>>(irows, NNZC, histU);
  k_scan<<<1,1024,0,stream>>>(histE, startE, cursorE, N_ENT);
  k_scan<<<1,1024,0,stream>>>(histU, startU, cursorU, N_USR);
  k_scatter_sortE<<<1024,256,0,stream>>>(head, tail, edge_type, N_EDGEC, cursorE, trS);
  k_scatter_sortU<<<512,256,0,stream>>>(irows, icols, inter_vals, NNZC, cursorU, icolsS, ivalsS);

  // build_adj #1 on original entity_emb (sim matrix staged in the adj output region)
  k_split<<<N_ENT/4,256,0,stream>>>(entity_emb, abufA, abufB);
  k_gemm_bf16<<<NTRI,256,0,stream>>>(abufA, abufB, adj, rowmax);
  k_topk<<<N_ENT,64,0,stream>>>(adj, rowmax, knn_idx0, knn_val0, rowsum0);

  // 2 hops (q for hop0 computed once; hop1's q fused into k_entfin)
  k_q<<<N_ENT/4,256,0,stream>>>(cur_ent, W, q);
  for(int hop=0; hop<2; ++hop){
    k_edge_agg<<<N_ENT,256,0,stream>>>(trS, startE, cur_ent, W, q, agg);
    k_user<<<N_USR/4,256,0,stream>>>(icolsS, ivalsS, startU, cur_ent, W, cur_usr, usr_res);
    k_entfin<<<N_ENT/4,256,0,stream>>>(agg, cur_ent, ent_res, W, q, hop==0);
  }

  // build_adj #2 on entity_res_emb
  k_split<<<N_ENT/4,256,0,stream>>>(ent_res, abufA, abufB);
  k_gemm_bf16<<<NTRI,256,0,stream>>>(abufA, abufB, adj, rowmax);
  k_topk<<<N_ENT,64,0,stream>>>(adj, rowmax, knn_idx1, knn_val1, rowsum1);

  // item_adj = 0.5*new + 0.5*origin, single-pass dense write (no memset, no atomics)
  k_write_adj<<<N_ENT,256,0,stream>>>(knn_idx0, knn_val0, rowsum0,
                                      knn_idx1, knn_val1, rowsum1, adj);
}

// Round 14
// 831.006 us; speedup vs baseline: 1.0677x; 1.0408x over previous
//
#include <hip/hip_runtime.h>
#include <hip/hip_bf16.h>

#define N_ENT   8192
#define N_USR   16384
#define CH      64
#define N_EDGEC 1000000
#define NNZC    500000
#define TOPKC   10
#define NRELM1  8
#define KSPLIT  384   // 6 limb-blocks of 64: A=[h,h,m,l,h,m], B=[h,m,h,h,l,m]
#define BKS     96    // K-step (4 steps of 96)
#define LDSP    104   // padded LDS row stride for main tiles
#define LDSTP   133   // padded row stride (floats) for the transpose chunk buffer
#define NTILE   64    // column tiles per row (8192/128)
#define NTRI    2080  // 64*65/2 upper-triangular tiles

typedef __bf16 bf16x8 __attribute__((ext_vector_type(8)));
typedef float  f32x4  __attribute__((ext_vector_type(4)));

static __device__ __forceinline__ float waveReduceSum(float v){
#pragma unroll
  for(int o=1;o<64;o<<=1) v += __shfl_xor(v,o,64);
  return v;
}
static __device__ __forceinline__ unsigned long long u64max(unsigned long long a, unsigned long long b){
  return a>b? a: b;
}
static __device__ __forceinline__ unsigned mapf(float v){
  unsigned u = __float_as_uint(v);
  return (u & 0x80000000u) ? ~u : (u | 0x80000000u);
}
static __device__ __forceinline__ float unmapf(unsigned mk){
  unsigned uo = (mk & 0x80000000u) ? (mk ^ 0x80000000u) : ~mk;
  return __uint_as_float(uo);
}
// f32 -> bf16 RTN-even (inputs finite)
static __device__ __forceinline__ ushort f2bf(float x){
  unsigned u = __float_as_uint(x);
  return (ushort)((u + 0x7FFFu + ((u>>16)&1u)) >> 16);
}
static __device__ __forceinline__ float bf2f(ushort h){
  return __uint_as_float((unsigned)h<<16);
}

// ---------------- init: residuals + working copies in one dispatch ----------------
__global__ __launch_bounds__(256) void k_init(const float* __restrict__ ue,
                                              const float* __restrict__ ee,
                                              float* __restrict__ usr_res,
                                              float* __restrict__ cur_usr,
                                              float* __restrict__ ent_res,
                                              float* __restrict__ cur_ent){
  int i = blockIdx.x*256 + threadIdx.x;                 // float4 index
  float4 v = ((const float4*)ue)[i];
  ((float4*)usr_res)[i] = v;
  ((float4*)cur_usr)[i] = v;
  if(i < N_ENT*(CH/4)){
    float4 w = ((const float4*)ee)[i];
    ((float4*)ent_res)[i] = w;
    ((float4*)cur_ent)[i] = w;
  }
}

// ---------------- sorting (counting sort by segment key) ----------------
__global__ void k_hist(const int* __restrict__ keys, int n, int* __restrict__ hist){
  int i = blockIdx.x*blockDim.x + threadIdx.x;
  int stride = gridDim.x*blockDim.x;
  for(; i<n; i+=stride) atomicAdd(&hist[keys[i]], 1);
}

__global__ __launch_bounds__(1024) void k_scan(const int* __restrict__ hist,
                                               int* __restrict__ start,
                                               int* __restrict__ cursor, int n){
  __shared__ int part[1024];
  int t = threadIdx.x;
  int chunk = n/1024;
  int base = t*chunk;
  int s = 0;
  for(int i=0;i<chunk;i++) s += hist[base+i];
  part[t] = s; __syncthreads();
  for(int off=1; off<1024; off<<=1){
    int v = (t>=off) ? part[t-off] : 0;
    __syncthreads();
    part[t] += v;
    __syncthreads();
  }
  int run = (t==0) ? 0 : part[t-1];
  for(int i=0;i<chunk;i++){
    start[base+i] = run; cursor[base+i] = run;
    run += hist[base+i];
  }
  if(t==1023) start[n] = run;
}

__global__ void k_scatter_sortE(const int* __restrict__ head,
                                const int* __restrict__ tail,
                                const int* __restrict__ etype, int n,
                                int* __restrict__ cursor, int* __restrict__ trS){
  int i = blockIdx.x*blockDim.x + threadIdx.x;
  int stride = gridDim.x*blockDim.x;
  for(; i<n; i+=stride){
    int pos = atomicAdd(&cursor[head[i]], 1);
    trS[pos] = (tail[i] & 8191) | ((etype[i]-1)<<13);
  }
}

__global__ void k_scatter_sortU(const int* __restrict__ irows,
                                const int* __restrict__ icols,
                                const float* __restrict__ ivals, int n,
                                int* __restrict__ cursor,
                                int* __restrict__ icolsS, float* __restrict__ ivalsS){
  int i = blockIdx.x*blockDim.x + threadIdx.x;
  int stride = gridDim.x*blockDim.x;
  for(; i<n; i+=stride){
    int pos = atomicAdd(&cursor[irows[i]], 1);
    icolsS[pos] = icols[i];
    ivalsS[pos] = ivals[i];
  }
}

// ---------------- normalize + triple-bf16 split into A/B limb layouts ----------------
__global__ __launch_bounds__(256) void k_split(const float* __restrict__ in,
                                               ushort* __restrict__ outA,
                                               ushort* __restrict__ outB){
  int wave = threadIdx.x>>6, lane = threadIdx.x&63;
  int r = blockIdx.x*4 + wave;
  float v = in[(size_t)r*CH+lane];
  float ss = waveReduceSum(v*v);
  float x = v / sqrtf(ss);
  ushort h = f2bf(x);
  float r1 = x - bf2f(h);
  ushort m = f2bf(r1);
  float r2 = r1 - bf2f(m);
  ushort l = f2bf(r2);
  ushort* oA = outA + (size_t)r*KSPLIT;
  ushort* oB = outB + (size_t)r*KSPLIT;
  oA[lane]     =h; oA[64+lane] =h; oA[128+lane]=m;
  oA[192+lane] =l; oA[256+lane]=h; oA[320+lane]=m;
  oB[lane]     =h; oB[64+lane] =m; oB[128+lane]=h;
  oB[192+lane] =h; oB[256+lane]=l; oB[320+lane]=m;
}

// ---------------- symmetric sim GEMM (upper-triangular blocks) ----------------
__global__ __launch_bounds__(256) void k_gemm_bf16(const ushort* __restrict__ A,
                                                   const ushort* __restrict__ B,
                                                   float* __restrict__ C,
                                                   float* __restrict__ rowmax){
  __shared__ __align__(16) ushort As[128*LDSP];
  __shared__ __align__(16) ushort Bs[128*LDSP];
  const int tid = threadIdx.x, lane = tid&63, wid = tid>>6;

  // decode linear block id -> (by, bx), by<=bx   S(r) = r*64 - r(r-1)/2
  int bid = blockIdx.x;
  int by = (int)((129.0f - sqrtf(16641.0f - 8.0f*(float)bid)) * 0.5f);
  while(((by+1)*64 - ((by+1)*by)/2) <= bid) by++;
  while((by*64 - (by*(by-1))/2) > bid) by--;
  int bx = by + (bid - (by*64 - (by*(by-1))/2));

  const int bi = by*128, bj = bx*128;
  const int wr = (wid>>1)*64, wc = (wid&1)*64;
  const int r16 = lane&15, kg = lane>>4;

  f32x4 acc[4][4] = {};

  const uint4* gA = (const uint4*)A + (size_t)bi*(KSPLIT/8);
  const uint4* gB = (const uint4*)B + (size_t)bj*(KSPLIT/8);
  const int row2 = tid>>1, half = tid&1;

  for(int s=0; s<KSPLIT/BKS; ++s){
    __syncthreads();
#pragma unroll
    for(int jj=0;jj<6;jj++){
      *(uint4*)&As[row2*LDSP + half*48 + jj*8] = gA[row2*(KSPLIT/8) + s*12 + half*6 + jj];
      *(uint4*)&Bs[row2*LDSP + half*48 + jj*8] = gB[row2*(KSPLIT/8) + s*12 + half*6 + jj];
    }
    __syncthreads();
#pragma unroll
    for(int kk=0;kk<3;kk++){
      bf16x8 a[4], b[4];
#pragma unroll
      for(int m=0;m<4;m++)
        a[m] = *(const bf16x8*)&As[(wr+m*16+r16)*LDSP + kk*32 + kg*8];
#pragma unroll
      for(int n=0;n<4;n++)
        b[n] = *(const bf16x8*)&Bs[(wc+n*16+r16)*LDSP + kk*32 + kg*8];
#pragma unroll
      for(int m=0;m<4;m++)
#pragma unroll
        for(int n=0;n<4;n++)
          acc[m][n] = __builtin_amdgcn_mfma_f32_16x16x32_bf16(a[m], b[n], acc[m][n], 0,0,0);
    }
  }

  // ---- direct tile store. C/D layout: col = lane&15, row = (lane>>4)*4 + reg ----
#pragma unroll
  for(int m=0;m<4;m++){
#pragma unroll
    for(int n=0;n<4;n++){
      size_t base = (size_t)(bi + wr + m*16 + kg*4)*N_ENT + (bj + wc + n*16 + r16);
      C[base]          = acc[m][n][0];
      C[base+N_ENT]    = acc[m][n][1];
      C[base+2*N_ENT]  = acc[m][n][2];
      C[base+3*N_ENT]  = acc[m][n][3];
    }
  }

  // ---- tmax: per-row max of this tile (over cols) ----
  float tmax[4][4];   // [m][reg]
#pragma unroll
  for(int m=0;m<4;m++){
#pragma unroll
    for(int rg=0;rg<4;rg++){
      float v = acc[m][0][rg];
      v = fmaxf(v, acc[m][1][rg]);
      v = fmaxf(v, acc[m][2][rg]);
      v = fmaxf(v, acc[m][3][rg]);
#pragma unroll
      for(int o=1;o<16;o<<=1) v = fmaxf(v, __shfl_xor(v, o, 64));
      tmax[m][rg] = v;
    }
  }
  // ---- cm: per-column max of this tile (over rows), for the mirror tile ----
  float cm[4];        // [n]
#pragma unroll
  for(int n=0;n<4;n++){
    float v = acc[0][n][0];
#pragma unroll
    for(int m=0;m<4;m++)
#pragma unroll
      for(int rg=0;rg<4;rg++) v = fmaxf(v, acc[m][n][rg]);
    v = fmaxf(v, __shfl_xor(v, 16, 64));
    v = fmaxf(v, __shfl_xor(v, 32, 64));
    cm[n] = v;
  }

  __syncthreads();                  // main-loop LDS reads done everywhere
  float* rm  = (float*)Bs;          // 128 floats: row maxes (combine wc halves)
  float* cmb = ((float*)Bs) + 128;  // 128 floats: col maxes (combine wr halves)
  if(((wid&1)==0) && r16==0){
#pragma unroll
    for(int m=0;m<4;m++)
#pragma unroll
      for(int rg=0;rg<4;rg++)
        rm[wr + m*16 + kg*4 + rg] = tmax[m][rg];
  }
  if(wid<2 && kg==0){               // wr==0 waves hold cols wc..wc+63
#pragma unroll
    for(int n=0;n<4;n++) cmb[wc + n*16 + r16] = cm[n];
  }
  __syncthreads();
  if(((wid&1)==1) && r16==0){       // direct rowmax: rows bi.., tile bx
#pragma unroll
    for(int m=0;m<4;m++)
#pragma unroll
      for(int rg=0;rg<4;rg++){
        int rrow = wr + m*16 + kg*4 + rg;
        rowmax[(size_t)(bi+rrow)*NTILE + bx] = fmaxf(tmax[m][rg], rm[rrow]);
      }
  }
  if(by != bx && wid>=2 && kg==0){  // mirror rowmax: rows bj.., tile by
#pragma unroll
    for(int n=0;n<4;n++){
      int ccol = wc + n*16 + r16;
      rowmax[(size_t)(bj+ccol)*NTILE + by] = fmaxf(cm[n], cmb[ccol]);
    }
  }

  // ---- mirror tile store via chunked LDS transpose (coalesced 128B rows) ----
  if(by != bx){
    float* ldsT = (float*)As;       // 32 x LDSTP floats = 17 KB (fits in As)
    for(int q=0;q<4;q++){
      __syncthreads();
#pragma unroll
      for(int n=0;n<4;n++){
        if(((wc>>5) + (n>>1)) == q){
          int cl = ((n&1)*16) + r16;      // local col in chunk, 0..31
#pragma unroll
          for(int m=0;m<4;m++)
#pragma unroll
            for(int rg=0;rg<4;rg++)
              ldsT[cl*LDSTP + wr + m*16 + kg*4 + rg] = acc[m][n][rg];
        }
      }
      __syncthreads();
      int cr = tid>>3;                    // 0..31
      int g  = tid&7;                     // 0..7
      float* crow = C + (size_t)(bj + q*32 + cr)*N_ENT + bi;
#pragma unroll
      for(int f=0; f<4; ++f){
        int cidx = (g + f*8)*4;           // 0,32,..124 dwords
        float4 v = *(float4*)&ldsT[cr*LDSTP + cidx];
        *(float4*)&crow[cidx] = v;
      }
    }
  }
}

// ---------------- per-row top-k via tile-max pruning, one wave per row ----------------
#define CANDCAP 256
__global__ __launch_bounds__(64) void k_topk(const float* __restrict__ S,
                                             const float* __restrict__ rowmax,
                                             int* __restrict__ knn_idx,
                                             float* __restrict__ knn_val,
                                             float* __restrict__ rowsum){
  const int row = blockIdx.x;
  const int lane = threadIdx.x;
  const float4* s4 = (const float4*)(S + (size_t)row*N_ENT);

  __shared__ unsigned long long cand[CANDCAP];
  __shared__ int tlist[NTILE];
  __shared__ int cnt, tcnt;
  if(lane==0){ cnt=0; tcnt=0; }
  __syncthreads();

  // exact 10th-largest tile max (lane id breaks ties -> unique removal)
  float tm = rowmax[(size_t)row*NTILE + lane];
  unsigned long long work = ((unsigned long long)mapf(tm)<<32) | (unsigned)lane;
  unsigned long long w = 0;
  for(int sel=0; sel<TOPKC; ++sel){
    w = work;
#pragma unroll
    for(int o=1;o<64;o<<=1) w = u64max(w, __shfl_xor(w,o,64));
    if(work == w) work = 0ull;
  }
  float tauf = unmapf((unsigned)(w>>32));

  if(tm >= tauf){ int p = atomicAdd(&tcnt,1); tlist[p] = lane; }
  __syncthreads();
  int nt = tcnt;

  // scan qualifying tiles, 2 tiles per iteration (32 lanes each)
  for(int i = (lane>>5); i < nt; i += 2){
    int t  = tlist[i];
    int fo = lane&31;
    float4 v = s4[t*32 + fo];
    int c0 = t*128 + fo*4;
    float vv[4] = {v.x,v.y,v.z,v.w};
#pragma unroll
    for(int j=0;j<4;j++){
      if(vv[j] >= tauf){
        int pos = atomicAdd(&cnt,1);
        if(pos < CANDCAP)
          cand[pos] = ((unsigned long long)mapf(vv[j])<<32)
                    | (unsigned long long)(0xFFFFFFFFu - (unsigned)(c0+j));
      }
    }
  }
  __syncthreads();
  int n = cnt;

  if(n <= CANDCAP){
    unsigned long long c0 = (lane      < n) ? cand[lane]       : 0ull;
    unsigned long long c1 = (lane+64   < n) ? cand[lane+64]    : 0ull;
    unsigned long long c2 = (lane+128  < n) ? cand[lane+128]   : 0ull;
    unsigned long long c3 = (lane+192  < n) ? cand[lane+192]   : 0ull;
    float rs = 0.f;
    for(int sel=0; sel<TOPKC; ++sel){
      unsigned long long m = u64max(u64max(c0,c1), u64max(c2,c3));
#pragma unroll
      for(int o=1;o<64;o<<=1) m = u64max(m, __shfl_xor(m,o,64));
      if(c0==m) c0=0ull; else if(c1==m) c1=0ull;
      else if(c2==m) c2=0ull; else if(c3==m) c3=0ull;
      if(lane==0){
        float v = unmapf((unsigned)(m>>32));
        int col = (int)(0xFFFFFFFFu - (unsigned)(m & 0xFFFFFFFFu));
        knn_idx[row*TOPKC+sel] = col;
        knn_val[row*TOPKC+sel] = v;
        rs += v;
      }
    }
    if(lane==0) rowsum[row] = rs;
  } else {
    // pathological fallback: exact register insertion scan over the full row
    unsigned long long loc[TOPKC];
#pragma unroll
    for(int i=0;i<TOPKC;i++) loc[i]=0ull;
    for(int it=0; it<N_ENT/256; ++it){
      int vi = it*64+lane;
      float4 v = s4[vi];
      int c0i = vi*4;
      float vv[4] = {v.x,v.y,v.z,v.w};
#pragma unroll
      for(int j=0;j<4;j++){
        unsigned u = mapf(vv[j]);
        unsigned long long key = ((unsigned long long)u<<32)
                               | (unsigned long long)(0xFFFFFFFFu - (unsigned)(c0i+j));
        if(key > loc[TOPKC-1]){
          unsigned long long t = key;
#pragma unroll
          for(int z=0; z<TOPKC; ++z){
            if(t > loc[z]){ unsigned long long tmp=loc[z]; loc[z]=t; t=tmp; }
          }
        }
      }
    }
    float rs = 0.f;
    for(int sel=0; sel<TOPKC; ++sel){
      unsigned long long m = loc[0];
#pragma unroll
      for(int o=1;o<64;o<<=1) m = u64max(m, __shfl_xor(m,o,64));
      if(loc[0] == m){
#pragma unroll
        for(int z=0;z<TOPKC-1;++z) loc[z]=loc[z+1];
        loc[TOPKC-1]=0ull;
      }
      if(lane==0){
        float v = unmapf((unsigned)(m>>32));
        int col = (int)(0xFFFFFFFFu - (unsigned)(m & 0xFFFFFFFFu));
        knn_idx[row*TOPKC+sel] = col;
        knn_val[row*TOPKC+sel] = v;
        rs += v;
      }
    }
    if(lane==0) rowsum[row] = rs;
  }
}

// ---------------- q[i][r] = ||ent_i * W_r||^2 ----------------
__global__ __launch_bounds__(256) void k_q(const float* __restrict__ ent,
                                           const float* __restrict__ W,
                                           float* __restrict__ q){
  int wave=threadIdx.x>>6, lane=threadIdx.x&63;
  int r = blockIdx.x*4+wave;
  if(r>=N_ENT) return;
  float x = ent[(size_t)r*CH+lane];
#pragma unroll
  for(int rel=0; rel<NRELM1; rel++){
    float tt = x*W[rel*CH+lane];
    float s = waveReduceSum(tt*tt);
    if(lane==0) q[r*NRELM1+rel]=s;
  }
}

// ---------------- per-head edge aggregation: 2-pass (lane-parallel exp) ----------------
// att <= 0.01 always (xavier W, l2-normed e) -> shift-free softmax is exact.
// Pass A (lane-parallel): e = exp(att) -> wbuf, accumulate denom.
// Pass B (serial broadcast walk): acc += wbuf[p]*inv*wr[r]*ent[tl][lane].
__global__ __launch_bounds__(256) void k_edge_agg(
    const int* __restrict__ trS, const int* __restrict__ startE,
    const float* __restrict__ ent, const float* __restrict__ W,
    const float* __restrict__ q, float* __restrict__ wbuf,
    float* __restrict__ agg){
  int wid=threadIdx.x>>6, lane=threadIdx.x&63;
  int h = blockIdx.x*4+wid;
  if(h>=N_ENT) return;
  int s = startE[h], e2 = startE[h+1];

  float qh[NRELM1];
#pragma unroll
  for(int r=0;r<NRELM1;r++) qh[r] = q[h*NRELM1+r];
  float wr[NRELM1];
#pragma unroll
  for(int r=0;r<NRELM1;r++) wr[r] = W[r*CH+lane];

  // pass A: lane-parallel exp + denom
  float dn = 0.f;
  for(int p=s+lane; p<e2; p+=64){
    int tr = trS[p];
    int tl = tr & 8191, r = tr>>13;
    float e = expf(qh[r]*q[tl*NRELM1+r]);
    wbuf[p] = e;
    dn += e;
  }
  dn = waveReduceSum(dn);
  float inv = (dn>0.f) ? 1.f/dn : 0.f;

  // pass B: serial aggregate (broadcast loads + per-lane ent vector load)
  float acc = 0.f;
  for(int p=s; p<e2; p++){
    int tr = trS[p];
    int tl = tr & 8191, r = tr>>13;
    acc = fmaf(wbuf[p]*inv*wr[r], ent[(size_t)tl*CH+lane], acc);
  }
  agg[(size_t)h*CH+lane] = acc;
}

// ---------------- per-user: sparse agg + gated score + l2norm + residual ----------------
__global__ __launch_bounds__(256) void k_user(
    const int* __restrict__ icolsS, const float* __restrict__ ivalsS,
    const int* __restrict__ startU,
    const float* __restrict__ ent, const float* __restrict__ W,
    float* __restrict__ usr, float* __restrict__ usr_res){
  int wave=threadIdx.x>>6, lane=threadIdx.x&63;
  int u = blockIdx.x*4+wave;
  if(u>=N_USR) return;
  float ue = usr[(size_t)u*CH+lane];
  float l[NRELM1];
#pragma unroll
  for(int r=0;r<NRELM1;r++) l[r] = waveReduceSum(ue*W[r*CH+lane]);
  float lm = l[0];
#pragma unroll
  for(int r=1;r<NRELM1;r++) lm = fmaxf(lm,l[r]);
  float se=0.f;
#pragma unroll
  for(int r=0;r<NRELM1;r++){ l[r]=expf(l[r]-lm); se+=l[r]; }
  float inv = 1.f/se;
  float g = 0.f;
#pragma unroll
  for(int r=0;r<NRELM1;r++) g = fmaf(l[r]*inv, W[r*CH+lane], g);
  float acc=0.f;
  int s=startU[u], e2=startU[u+1];
  for(int p=s;p<e2;p++){
    acc = fmaf(ivalsS[p], ent[(size_t)icolsS[p]*CH+lane], acc);
  }
  float res = acc*(1.f+g);
  float nrm = sqrtf(waveReduceSum(res*res));
  float outv = res / fmaxf(nrm, 1e-12f);
  usr_res[(size_t)u*CH+lane] += outv;
  usr[(size_t)u*CH+lane] = outv;
}

// ---------------- entity finalize: l2norm + residual (+ fused next-hop q) ----------------
__global__ __launch_bounds__(256) void k_entfin(const float* __restrict__ agg,
                                                float* __restrict__ cur,
                                                float* __restrict__ res,
                                                const float* __restrict__ W,
                                                float* __restrict__ q, int makeq){
  int wave=threadIdx.x>>6, lane=threadIdx.x&63;
  int r = blockIdx.x*4+wave;
  if(r>=N_ENT) return;
  float v = agg[(size_t)r*CH+lane];
  float nrm = sqrtf(waveReduceSum(v*v));
  float outv = v / fmaxf(nrm, 1e-12f);
  cur[(size_t)r*CH+lane]=outv;
  res[(size_t)r*CH+lane]+=outv;
  if(makeq){
#pragma unroll
    for(int rel=0; rel<NRELM1; rel++){
      float tt = outv*W[rel*CH+lane];
      float s = waveReduceSum(tt*tt);
      if(lane==0) q[r*NRELM1+rel]=s;
    }
  }
}

// ---------------- fused adj writer: coalesced zeros, then direct patch ----------------
__global__ __launch_bounds__(256) void k_write_adj(
    const int* __restrict__ ki0, const float* __restrict__ kv0,
    const float* __restrict__ rs0,
    const int* __restrict__ ki1, const float* __restrict__ kv1,
    const float* __restrict__ rs1,
    float* __restrict__ adj){
  const int row = blockIdx.x;
  const int t = threadIdx.x;
  __shared__ int   cols[2*TOPKC];
  __shared__ float vals[2*TOPKC];

  if(t < TOPKC){
    int c = ki1[row*TOPKC+t];
    cols[t] = c;
    vals[t] = 0.5f * kv1[row*TOPKC+t] / (sqrtf(rs1[row]) * sqrtf(rs1[c]));
  } else if(t < 2*TOPKC){
    int i = t - TOPKC;
    int c = ki0[row*TOPKC+i];
    cols[t] = c;
    vals[t] = 0.5f * kv0[row*TOPKC+i] / (sqrtf(rs0[row]) * sqrtf(rs0[c]));
  }
  __syncthreads();
  if(t==0){
    for(int i=TOPKC;i<2*TOPKC;i++){
      int c = cols[i];
      for(int j=0;j<TOPKC;j++){
        if(cols[j]==c){ vals[j]+=vals[i]; cols[i]=-1; break; }
      }
    }
  }
  __syncthreads();

  float4* adj4 = (float4*)(adj + (size_t)row*N_ENT);
  float4 z = {0.f,0.f,0.f,0.f};
#pragma unroll
  for(int k=0;k<8;k++) adj4[k*256 + t] = z;
  __syncthreads();
  if(t < 2*TOPKC){
    int c = cols[t];
    if(c >= 0) adj[(size_t)row*N_ENT + c] = vals[t];
  }
}

extern "C" void kernel_launch(void* const* d_in, const int* in_sizes, int n_in,
                              void* d_out, int out_size, void* d_ws, size_t ws_size,
                              hipStream_t stream){
  const float* user_emb   = (const float*)d_in[0];
  const float* entity_emb = (const float*)d_in[1];
  const int*   edge_index = (const int*)d_in[2];
  const int*   edge_type  = (const int*)d_in[3];
  const int*   inter_idx  = (const int*)d_in[4];
  const float* inter_vals = (const float*)d_in[5];
  const float* W          = (const float*)d_in[6];

  const int* head  = edge_index;
  const int* tail  = edge_index + N_EDGEC;
  const int* irows = inter_idx;
  const int* icols = inter_idx + NNZC;

  float* out     = (float*)d_out;
  float* ent_res = out;
  float* usr_res = out + (size_t)N_ENT*CH;
  float* adj     = out + (size_t)N_ENT*CH + (size_t)N_USR*CH;

  char* wp = (char*)d_ws;
  auto alloc = [&](size_t bytes)->void*{
    void* p = (void*)wp; wp += (bytes+255)/256*256; return p;
  };
  ushort* abufA  = (ushort*)alloc((size_t)N_ENT*KSPLIT*2);
  ushort* abufB  = (ushort*)alloc((size_t)N_ENT*KSPLIT*2);
  float* rowmax  = (float*)alloc((size_t)N_ENT*NTILE*4);
  float* cur_ent = (float*)alloc((size_t)N_ENT*CH*4);
  float* cur_usr = (float*)alloc((size_t)N_USR*CH*4);
  float* agg     = (float*)alloc((size_t)N_ENT*CH*4);
  float* q       = (float*)alloc((size_t)N_ENT*NRELM1*4);
  int*   histE   = (int*)alloc((size_t)N_ENT*4);
  int*   startE  = (int*)alloc((size_t)(N_ENT+1)*4);
  int*   cursorE = (int*)alloc((size_t)N_ENT*4);
  int*   trS     = (int*)alloc((size_t)N_EDGEC*4);
  int*   histU   = (int*)alloc((size_t)N_USR*4);
  int*   startU  = (int*)alloc((size_t)(N_USR+1)*4);
  int*   cursorU = (int*)alloc((size_t)N_USR*4);
  int*   icolsS  = (int*)alloc((size_t)NNZC*4);
  float* ivalsS  = (float*)alloc((size_t)NNZC*4);
  int*   knn_idx0= (int*)alloc((size_t)N_ENT*TOPKC*4);
  float* knn_val0= (float*)alloc((size_t)N_ENT*TOPKC*4);
  float* rowsum0 = (float*)alloc((size_t)N_ENT*4);
  int*   knn_idx1= (int*)alloc((size_t)N_ENT*TOPKC*4);
  float* knn_val1= (float*)alloc((size_t)N_ENT*TOPKC*4);
  float* rowsum1 = (float*)alloc((size_t)N_ENT*4);

  // wbuf for edge softmax lives in the adj output region (256MB, idle during hops)
  float* wbuf = adj;

  // init (one dispatch: residuals + working copies)
  hipMemsetAsync(histE, 0, (size_t)N_ENT*4, stream);
  hipMemsetAsync(histU, 0, (size_t)N_USR*4, stream);
  k_init<<<N_USR*(CH/4)/256,256,0,stream>>>(user_emb, entity_emb,
                                            usr_res, cur_usr, ent_res, cur_ent);

  // counting sorts with fused payload gather (edges by head, inter by row)
  k_hist<<<1024,256,0,stream>>>(head, N_EDGEC, histE);
  k_hist<<<512,256,0,stream>>>(irows, NNZC, histU);
  k_scan<<<1,1024,0,stream>>>(histE, startE, cursorE, N_ENT);
  k_scan<<<1,1024,0,stream>>>(histU, startU, cursorU, N_USR);
  k_scatter_sortE<<<1024,256,0,stream>>>(head, tail, edge_type, N_EDGEC, cursorE, trS);
  k_scatter_sortU<<<512,256,0,stream>>>(irows, icols, inter_vals, NNZC, cursorU, icolsS, ivalsS);

  // build_adj #1 on original entity_emb (sim matrix staged in the adj output region)
  k_split<<<N_ENT/4,256,0,stream>>>(entity_emb, abufA, abufB);
  k_gemm_bf16<<<NTRI,256,0,stream>>>(abufA, abufB, adj, rowmax);
  k_topk<<<N_ENT,64,0,stream>>>(adj, rowmax, knn_idx0, knn_val0, rowsum0);

  // 2 hops (q for hop0 computed once; hop1's q fused into k_entfin)
  k_q<<<N_ENT/4,256,0,stream>>>(cur_ent, W, q);
  for(int hop=0; hop<2; ++hop){
    k_edge_agg<<<N_ENT/4,256,0,stream>>>(trS, startE, cur_ent, W, q, wbuf, agg);
    k_user<<<N_USR/4,256,0,stream>>>(icolsS, ivalsS, startU, cur_ent, W, cur_usr, usr_res);
    k_entfin<<<N_ENT/4,256,0,stream>>>(agg, cur_ent, ent_res, W, q, hop==0);
  }

  // build_adj #2 on entity_res_emb
  k_split<<<N_ENT/4,256,0,stream>>>(ent_res, abufA, abufB);
  k_gemm_bf16<<<NTRI,256,0,stream>>>(abufA, abufB, adj, rowmax);
  k_topk<<<N_ENT,64,0,stream>>>(adj, rowmax, knn_idx1, knn_val1, rowsum1);

  // item_adj = 0.5*new + 0.5*origin, single-pass dense write (no memset, no atomics)
  k_write_adj<<<N_ENT,256,0,stream>>>(knn_idx0, knn_val0, rowsum0,
                                      knn_idx1, knn_val1, rowsum1, adj);
}